// Round 10
// baseline (494.793 us; speedup 1.0000x reference)
//
#include <hip/hip_runtime.h>

typedef unsigned short u16;
typedef __attribute__((ext_vector_type(8))) _Float16 f16x8;
typedef __attribute__((ext_vector_type(4))) float f32x4;

#define MFMAH(a, b, c) __builtin_amdgcn_mfma_f32_16x16x32_f16((a), (b), (c), 0, 0, 0)

__device__ __forceinline__ u16 f2h(float f) {
  _Float16 h = (_Float16)f;  // v_cvt_f16_f32, RNE
  return __builtin_bit_cast(u16, h);
}
__device__ __forceinline__ float h2f(u16 h) {
  return (float)__builtin_bit_cast(_Float16, h);
}
__device__ __forceinline__ unsigned pk_h(float a, float b) {
  return (unsigned)f2h(a) | ((unsigned)f2h(b) << 16);
}

// ---------------- x: fp32 -> f16 hi + f16 lo (x = hi + lo exact to ~2^-23) ----------------
__global__ void splitf16_kernel(const float* __restrict__ in, u16* __restrict__ hi,
                                u16* __restrict__ lo, long n4) {
  long stride = (long)gridDim.x * blockDim.x;
  for (long i = (long)blockIdx.x * blockDim.x + threadIdx.x; i < n4; i += stride) {
    float4 v = ((const float4*)in)[i];
    ushort4 h, l;
    h.x = f2h(v.x); l.x = f2h(v.x - h2f(h.x));
    h.y = f2h(v.y); l.y = f2h(v.y - h2f(h.y));
    h.z = f2h(v.z); l.z = f2h(v.z - h2f(h.z));
    h.w = f2h(v.w); l.w = f2h(v.w - h2f(h.w));
    ((ushort4*)hi)[i] = h;
    ((ushort4*)lo)[i] = l;
  }
}

// ---------------- weights: fp32 -> f16 single ----------------
__global__ void castf16_kernel(const float* __restrict__ in, u16* __restrict__ out, long n4) {
  long stride = (long)gridDim.x * blockDim.x;
  for (long i = (long)blockIdx.x * blockDim.x + threadIdx.x; i < n4; i += stride) {
    float4 v = ((const float4*)in)[i];
    ushort4 h;
    h.x = f2h(v.x); h.y = f2h(v.y); h.z = f2h(v.z); h.w = f2h(v.w);
    ((ushort4*)out)[i] = h;
  }
}

// ---------------- cos/sin table: (b, t-1, i) -> float2(c,s); 16 heads share positions ----------------
__global__ void cs_table_kernel(const int* __restrict__ pos, float2* __restrict__ cst) {
  int idx = blockIdx.x * 256 + threadIdx.x;  // exactly B*2048*32 threads
  int i = idx & 31;
  int r = idx >> 5;
  int ti = r & 2047;
  int b = r >> 11;
  int p = pos[b * 2048 + ti];
  // replicate reference fp32 rounding of freq and angle, then exact trig
  float fr = (float)pow(10000.0, -(double)i / 32.0);
  float angf = (float)p * fr;
  double sd, cd;
  sincos((double)angf, &sd, &cd);
  cst[idx] = make_float2((float)cd, (float)sd);
}

// ---------------- K pad rows [N, NP): zero (f16 single) ----------------
__global__ void kpad_kernel(u16* __restrict__ kh, int N, int NP) {
  const int per_bh = (NP - N) * 32;  // u32 words per bh
  int idx = blockIdx.x * 256 + threadIdx.x;
  if (idx >= 64 * per_bh) return;
  int bh = idx / per_bh, r = idx - bh * per_bh;
  size_t u = (((size_t)bh * NP + N) * 64 >> 1) + r;
  ((unsigned*)kh)[u] = 0;
}

// ---------------- V transpose: f16 [bh][N][64] -> [bh][64][NP], zero-padded ----------------
__global__ __launch_bounds__(256) void vtransT_kernel(const u16* __restrict__ vb_,
                                                      u16* __restrict__ ot, int N, int NP) {
  __shared__ u16 tile[64][72];
  const int bh = blockIdx.y;
  const int t0 = blockIdx.x * 64;
  const u16* ih = vb_ + (size_t)bh * N * 64;
#pragma unroll
  for (int p = 0; p < 4; ++p) {
    int idx = p * 256 + threadIdx.x;  // 1024 chunks of 4 u16
    int tloc = idx >> 4, c = (idx & 15) * 4;
    int t = t0 + tloc;
    ushort4 a = make_ushort4(0, 0, 0, 0);
    if (t < N) a = *(const ushort4*)(ih + (size_t)t * 64 + c);
    *(ushort4*)&tile[tloc][c] = a;
  }
  __syncthreads();
  u16* oh = ot + (size_t)bh * 64 * NP;
#pragma unroll
  for (int p = 0; p < 4; ++p) {
    int idx = p * 256 + threadIdx.x;  // d (64) x tquad (16)
    int d = idx >> 4, tq = (idx & 15) * 4;
    int t = t0 + tq;
    if (t < NP) {
      ushort4 a;
      a.x = tile[tq + 0][d]; a.y = tile[tq + 1][d];
      a.z = tile[tq + 2][d]; a.w = tile[tq + 3][d];
      *(ushort4*)(oh + (size_t)d * NP + t) = a;
    }
  }
}

// ================= 3-buffer counted-vmcnt f16x2 GEMM (T4 without fine phases) =================
// C = (Ah+Al)(MxK) * W(NxK)^T + bias.  BM=256 x BN=128 x BK=32; 512 thr = 8 waves (4M x 2N),
// wave tile 64x64.  THREE LDS buffers -> stage runs 2 K-tiles ahead; ONE raw s_barrier and
// ONE counted s_waitcnt vmcnt(5) per K-step (tile t+2's 5 loads stay in flight across the
// barrier — never drained to 0 in steady state).  No intra-step barriers (R9 lesson: 8
// barriers/step at 1 block/CU swamped the MFMA demand).  Compiler handles ds_read->MFMA
// lgkmcnt.  T2 source-side swizzle (conflicts 0).
__device__ __forceinline__ int swz_off(int R, int lg) {
  return R * 32 + ((lg ^ ((R >> 1) & 3)) << 3);
}

template <int NI>
__device__ __forceinline__ void stageN(const u16* __restrict__ g, u16* l, int row0, int rmax,
                                       int K, int k0, int tid) {
#pragma unroll
  for (int t = 0; t < NI; ++t) {
    int c = t * 512 + tid;
    int row = c >> 2;
    int kc = (((c & 3) ^ ((c >> 3) & 3)) << 3);  // pre-swizzled source granule
    int gr = row0 + row;
    if (gr > rmax) gr = rmax;
    const u16* gp = g + (size_t)gr * K + (k0 + kc);
    __builtin_amdgcn_global_load_lds((const __attribute__((address_space(1))) void*)gp,
                                     (__attribute__((address_space(3))) void*)(l + c * 8),
                                     16, 0, 0);
  }
}

template <int EPI>
__global__ __launch_bounds__(512) void gemm_p3(
    const u16* __restrict__ Ah, const u16* __restrict__ Al, const u16* __restrict__ Bw,
    const float* __restrict__ bias, const float2* __restrict__ cst,
    float* __restrict__ outf,
    u16* __restrict__ oq, u16* __restrict__ ok, u16* __restrict__ ov,
    int M, int Nn, int K, int Ntok, int NP) {
  __shared__ u16 AbH[3][8192], AbL[3][8192], WbS[3][4096];  // 3 x (16+16+8) KB = 120 KB
  const int tid = threadIdx.x;
  const int wid = tid >> 6, lane = tid & 63;
  const int wm = wid >> 1, wn = wid & 1;
  const int lg = lane >> 4, lm = lane & 15;
  // XCD-bijective swizzle (grid % 8 == 0); N-dim fastest so one XCD shares A panels
  const int id = blockIdx.x;
  const int nx = Nn >> 7;
  const int swz = (id & 7) * ((int)gridDim.x >> 3) + (id >> 3);
  const int mbase = (swz / nx) * 256, nbase = (swz % nx) * 128;

  f32x4 acc[4][4];
  const f32x4 zero = {0.f, 0.f, 0.f, 0.f};
#pragma unroll
  for (int a = 0; a < 4; ++a)
#pragma unroll
    for (int b = 0; b < 4; ++b) acc[a][b] = zero;

  // prologue: stage tiles 0 and 1 (10 loads); wait tile 0 only (tile 1 stays in flight)
  stageN<2>(Ah, AbH[0], mbase, M - 1, K, 0, tid);
  stageN<2>(Al, AbL[0], mbase, M - 1, K, 0, tid);
  stageN<1>(Bw, WbS[0], nbase, Nn - 1, K, 0, tid);
  stageN<2>(Ah, AbH[1], mbase, M - 1, K, 32, tid);
  stageN<2>(Al, AbL[1], mbase, M - 1, K, 32, tid);
  stageN<1>(Bw, WbS[1], nbase, Nn - 1, K, 32, tid);
  asm volatile("s_waitcnt vmcnt(5)" ::: "memory");
  asm volatile("s_barrier" ::: "memory");

  const int T = K >> 5;  // K-tiles of 32
  int cur = 0;
  for (int t = 0; t < T; ++t) {
    int nxt = cur + 2; if (nxt >= 3) nxt -= 3;
    // stage tile t+2 into the buffer last read at step t-1 (safe: its reads finished
    // before the end-of-(t-1) barrier)
    if (t + 2 < T) {
      const int k2 = (t + 2) << 5;
      stageN<2>(Ah, AbH[nxt], mbase, M - 1, K, k2, tid);
      stageN<2>(Al, AbL[nxt], mbase, M - 1, K, k2, tid);
      stageN<1>(Bw, WbS[nxt], nbase, Nn - 1, K, k2, tid);
    }
    // compute tile t from buf[cur] (landed: guaranteed by last step's vmcnt(5))
    const u16* cAh = AbH[cur];
    const u16* cAl = AbL[cur];
    const u16* cW = WbS[cur];
    f16x8 ah[4], al[4], w[4];
#pragma unroll
    for (int f = 0; f < 4; ++f) {
      ah[f] = *(const f16x8*)&cAh[swz_off(wm * 64 + f * 16 + lm, lg)];
      al[f] = *(const f16x8*)&cAl[swz_off(wm * 64 + f * 16 + lm, lg)];
      w[f] = *(const f16x8*)&cW[swz_off(wn * 64 + f * 16 + lm, lg)];
    }
#pragma unroll
    for (int fm = 0; fm < 4; ++fm)
#pragma unroll
      for (int fn = 0; fn < 4; ++fn) {
        acc[fm][fn] = MFMAH(ah[fm], w[fn], acc[fm][fn]);
        acc[fm][fn] = MFMAH(al[fm], w[fn], acc[fm][fn]);
      }
    // counted wait: tile t+1's loads done; tile t+2's 5 stay in flight across the barrier
    if (t < T - 2) {
      asm volatile("s_waitcnt vmcnt(5)" ::: "memory");
    } else if (t == T - 2) {
      asm volatile("s_waitcnt vmcnt(0)" ::: "memory");
    }
    asm volatile("s_barrier" ::: "memory");
    cur = cur + 1; if (cur >= 3) cur = 0;
  }

  const int which = (EPI == 0) ? (nbase >> 10) : 1;
  const bool odd = (lm & 1);

#pragma unroll
  for (int fm = 0; fm < 4; ++fm)
#pragma unroll
    for (int fn = 0; fn < 4; ++fn) {
      int col = nbase + wn * 64 + fn * 16 + lm;
      float bv = bias[col];
      int h2 = (col >> 6) & 15, d2 = col & 63;
#pragma unroll
      for (int i = 0; i < 4; ++i) {
        int row = mbase + wm * 64 + fm * 16 + lg * 4 + i;
        float v = acc[fm][fn][i] + bv;
        float partner = __shfl_xor(v, 1);  // neighbor column (re<->im), uniform exec
        if (row < M) {
          if (EPI == 1) {
            outf[(size_t)row * Nn + col] = v;
          } else {
            int b2 = row / Ntok, t2 = row - b2 * Ntok;
            int bh2 = b2 * 16 + h2;
            if (which == 2) {  // v: f16 single, row-major
              ov[((size_t)bh2 * Ntok + t2) * 64 + d2] = f2h(v);
            } else {
              // rope: even lane = re, odd lane = im
              float out = v;
              if (t2 > 0) {
                float2 cs = cst[((size_t)(b2 << 11) + (t2 - 1)) * 32 + (d2 >> 1)];
                out = v * cs.x + (odd ? partner * cs.y : -partner * cs.y);
              }
              if (which == 0) {  // q: fold softmax scale & exp2 conversion, f16 single
                out *= 0.18033688011112042f;  // 0.125 * log2(e)
                oq[((size_t)bh2 * Ntok + t2) * 64 + d2] = f2h(out);
              } else {  // k: f16 single, padded row allocation [bh][NP][64]
                ok[((size_t)bh2 * NP + t2) * 64 + d2] = f2h(out);
              }
            }
          }
        }
      }
    }
}

// ---------------- flash attention v5: 8-wave blocks, 256 q-rows, KVBLK=64, 2-phase ----------------
// K tile LDS (8KB): chunk rK*64+key -> K[key][rK*8..+8]  (rK = d-octet 0..7)
// V tile LDS (8KB): chunk kr*64+d   -> V^T[d][kv+kr*8..+8] (kr = key-octet 0..7)
template <bool DO_STAGE, bool TAIL>
__device__ __forceinline__ void attn_tile(
    int kv0, int kvn,
    const u16* Kc, const u16* Vc, u16* Kn, u16* Vn,
    const u16* kgb, const u16* vgb,
    int tid, int lg, int lm, int kvbase,
    const f16x8 (&qf16)[2][2],
    float (&m_)[2], float (&l_)[2], f32x4 (&oacc)[2][4],
    unsigned (*pexw)[4], int N) {
  if (DO_STAGE) {  // stage NEXT tile (other buffer); latency hides under this tile's compute
    __builtin_amdgcn_global_load_lds(
        (const __attribute__((address_space(1))) void*)(kgb + (size_t)kvn * 64),
        (__attribute__((address_space(3))) void*)(Kn + tid * 8), 16, 0, 0);
    __builtin_amdgcn_global_load_lds(
        (const __attribute__((address_space(1))) void*)(vgb + kvn),
        (__attribute__((address_space(3))) void*)(Vn + tid * 8), 16, 0, 0);
  }

  const f32x4 zero = {0.f, 0.f, 0.f, 0.f};
  f32x4 s[2][4];
#pragma unroll
  for (int qf = 0; qf < 2; ++qf)
#pragma unroll
    for (int cf = 0; cf < 4; ++cf) s[qf][cf] = zero;
#pragma unroll
  for (int cf = 0; cf < 4; ++cf)
#pragma unroll
    for (int dk = 0; dk < 2; ++dk) {
      f16x8 kf = *(const f16x8*)&Kc[kvbase + dk * 2048 + cf * 128];
      s[0][cf] = MFMAH(kf, qf16[0][dk], s[0][cf]);
      s[1][cf] = MFMAH(kf, qf16[1][dk], s[1][cf]);
    }
  if (TAIL) {
#pragma unroll
    for (int qf = 0; qf < 2; ++qf)
#pragma unroll
      for (int cf = 0; cf < 4; ++cf)
#pragma unroll
        for (int i = 0; i < 4; ++i)
          if (kv0 + cf * 16 + lg * 4 + i >= N) s[qf][cf][i] = -1e30f;
  }

  f16x8 pb[2][2];  // [qf][ks]
  const int ga = (lg & 1) * 2, gb = ga + 1;
  const int cfs2 = (lg >> 1) * 2;
#pragma unroll
  for (int qf = 0; qf < 2; ++qf) {
    float mx = s[qf][0][0];
#pragma unroll
    for (int cf = 0; cf < 4; ++cf)
#pragma unroll
      for (int i = 0; i < 4; ++i) mx = fmaxf(mx, s[qf][cf][i]);
    mx = fmaxf(mx, __shfl_xor(mx, 16));
    mx = fmaxf(mx, __shfl_xor(mx, 32));
    float mr = m_[qf];
    bool nore = __all(mx - mr <= 8.f) != 0;  // defer-max, THR=8 in log2 domain
    float mnew = nore ? mr : fmaxf(mr, mx);
    float p[16];
#pragma unroll
    for (int cf = 0; cf < 4; ++cf)
#pragma unroll
      for (int i = 0; i < 4; ++i)
        p[cf * 4 + i] = __builtin_amdgcn_exp2f(s[qf][cf][i] - mnew);
    float ps = 0.f;
#pragma unroll
    for (int j = 0; j < 16; ++j) ps += p[j];
    ps += __shfl_xor(ps, 16);
    ps += __shfl_xor(ps, 32);
    if (nore) {
      l_[qf] += ps;
    } else {
      float sc = __builtin_amdgcn_exp2f(mr - mnew);
      l_[qf] = l_[qf] * sc + ps;
      m_[qf] = mnew;
#pragma unroll
      for (int c = 0; c < 4; ++c)
#pragma unroll
        for (int i = 0; i < 4; ++i) oacc[qf][c][i] *= sc;
    }
    // pack P -> f16, redistribute to B-frag via wave-private LDS (DS in-order per wave)
#pragma unroll
    for (int ks = 0; ks < 2; ++ks) {
      uint4 uw;
      uw.x = pk_h(p[ks * 8 + 0], p[ks * 8 + 1]);
      uw.y = pk_h(p[ks * 8 + 2], p[ks * 8 + 3]);
      uw.z = pk_h(p[ks * 8 + 4], p[ks * 8 + 5]);
      uw.w = pk_h(p[ks * 8 + 6], p[ks * 8 + 7]);
      *(uint4*)&pexw[lg * 16 + lm][0] = uw;
      uint2 r0 = *(const uint2*)&pexw[ga * 16 + lm][cfs2];
      uint2 r1 = *(const uint2*)&pexw[gb * 16 + lm][cfs2];
      uint4 pu = make_uint4(r0.x, r0.y, r1.x, r1.y);
      pb[qf][ks] = __builtin_bit_cast(f16x8, pu);
    }
  }

#pragma unroll
  for (int c = 0; c < 4; ++c)
#pragma unroll
    for (int ks = 0; ks < 2; ++ks) {
      f16x8 vh = *(const f16x8*)&Vc[kvbase + ks * 2048 + c * 128];
      oacc[0][c] = MFMAH(vh, pb[0][ks], oacc[0][c]);
      oacc[1][c] = MFMAH(vh, pb[1][ks], oacc[1][c]);
    }
}

__global__ __launch_bounds__(512, 4) void attn_kernel(
    const u16* __restrict__ qh, const u16* __restrict__ kh, const u16* __restrict__ vth,
    u16* __restrict__ outh, u16* __restrict__ outl, int N, int NP) {
  __shared__ u16 K0[4096], V0[4096], K1[4096], V1[4096];
  __shared__ unsigned pexm[8][64][4];

  const int id = blockIdx.x;
  const int swz = (id & 7) * 72 + (id >> 3);  // XCD-bijective (576 = 8*72)
  const int qblk = swz % 9;
  const int bh = swz / 9;
  const int b = bh >> 4, h = bh & 15;
  const int tid = threadIdx.x;
  const int wid = tid >> 6, lane = tid & 63;
  const int lg = lane >> 4, lm = lane & 15;
  const int qbase = qblk * 256 + wid * 32;
  const size_t qoff = (size_t)bh * N * 64;
  const size_t koff = (size_t)bh * NP * 64;
  const size_t voff = (size_t)bh * 64 * NP;

  // staging sources: K thread t -> row (t&63), d-octet (t>>6); V thread t -> d (t&63), key-octet (t>>6)
  const int jK = tid & 63, rK = tid >> 6;
  const u16* kgb = kh + koff + (size_t)jK * 64 + rK * 8;
  const u16* vgb = vth + voff + (size_t)jK * NP + rK * 8;
  const int kvbase = lg * 512 + lm * 8;  // + dk|ks*2048 + cf|c*128

  f16x8 qf16[2][2];
#pragma unroll
  for (int qf = 0; qf < 2; ++qf) {
    int qr = qbase + qf * 16 + lm;
    if (qr > N - 1) qr = N - 1;
    const u16* qp = qh + qoff + (size_t)qr * 64 + lg * 8;
    qf16[qf][0] = *(const f16x8*)(qp);
    qf16[qf][1] = *(const f16x8*)(qp + 32);
  }

  const f32x4 zero = {0.f, 0.f, 0.f, 0.f};
  f32x4 oacc[2][4];
#pragma unroll
  for (int qf = 0; qf < 2; ++qf)
#pragma unroll
    for (int c = 0; c < 4; ++c) oacc[qf][c] = zero;
  float m_[2] = {-1e30f, -1e30f}, l_[2] = {0.f, 0.f};
  unsigned(*pexw)[4] = &pexm[wid][0];

  // prologue: stage tile 0 into buffer 0
  __builtin_amdgcn_global_load_lds(
      (const __attribute__((address_space(1))) void*)kgb,
      (__attribute__((address_space(3))) void*)(K0 + tid * 8), 16, 0, 0);
  __builtin_amdgcn_global_load_lds(
      (const __attribute__((address_space(1))) void*)vgb,
      (__attribute__((address_space(3))) void*)(V0 + tid * 8), 16, 0, 0);
  asm volatile("s_waitcnt vmcnt(0)" ::: "memory");
  __builtin_amdgcn_s_barrier();

  // tiles 0..31 in pairs (stage t+1 during t), tile 32 = tail (keys 2048..2111, padded)
  for (int t = 0; t < 32; t += 2) {
    attn_tile<true, false>(t * 64, (t + 1) * 64, K0, V0, K1, V1, kgb, vgb,
                           tid, lg, lm, kvbase, qf16, m_, l_, oacc, pexw, N);
    asm volatile("s_waitcnt vmcnt(0)" ::: "memory");
    __builtin_amdgcn_s_barrier();
    attn_tile<true, false>((t + 1) * 64, (t + 2) * 64, K1, V1, K0, V0, kgb, vgb,
                           tid, lg, lm, kvbase, qf16, m_, l_, oacc, pexw, N);
    asm volatile("s_waitcnt vmcnt(0)" ::: "memory");
    __builtin_amdgcn_s_barrier();
  }
  attn_tile<false, true>(32 * 64, 0, K0, V0, K1, V1, kgb, vgb,
                         tid, lg, lm, kvbase, qf16, m_, l_, oacc, pexw, N);

  // epilogue: O/l -> f16 hi/lo (feeds final f16x2 GEMM)
#pragma unroll
  for (int qf = 0; qf < 2; ++qf) {
    int t = qbase + qf * 16 + lm;
    if (t < N) {
      float rl = 1.f / l_[qf];
      size_t rowoff = ((size_t)(b * N + t)) * 1024 + h * 64 + lg * 4;
#pragma unroll
      for (int c = 0; c < 4; ++c) {
        float v0 = oacc[qf][c][0] * rl, v1 = oacc[qf][c][1] * rl;
        float v2 = oacc[qf][c][2] * rl, v3 = oacc[qf][c][3] * rl;
        u16 h0 = f2h(v0), h1 = f2h(v1), h2 = f2h(v2), h3 = f2h(v3);
        unsigned hh01 = (unsigned)h0 | ((unsigned)h1 << 16);
        unsigned hh23 = (unsigned)h2 | ((unsigned)h3 << 16);
        unsigned ll01 = pk_h(v0 - h2f(h0), v1 - h2f(h1));
        unsigned ll23 = pk_h(v2 - h2f(h2), v3 - h2f(h3));
        *(uint2*)(outh + rowoff + c * 16) = make_uint2(hh01, hh23);
        *(uint2*)(outl + rowoff + c * 16) = make_uint2(ll01, ll23);
      }
    }
  }
}

// ---------------- orchestration ----------------
extern "C" void kernel_launch(void* const* d_in, const int* in_sizes, int n_in,
                              void* d_out, int out_size, void* d_ws, size_t ws_size,
                              hipStream_t stream) {
  const float* x     = (const float*)d_in[0];
  const int*   pos   = (const int*)  d_in[1];
  const float* w_qkv = (const float*)d_in[2];
  const float* b_qkv = (const float*)d_in[3];
  const float* w_fc  = (const float*)d_in[4];
  const float* b_fc  = (const float*)d_in[5];
  (void)in_sizes; (void)n_in; (void)out_size; (void)ws_size;

  const int B = 4, N = 2049, NP = 2112;  // NP = 33*64 (KVBLK=64 tiles)
  const long EL = (long)B * N * 1024;       // 8,392,704
  const long ELP = (long)B * 16 * NP * 64;  // padded K elems

  char* base = (char*)d_ws;
  size_t off = 0;
  auto alloc = [&](size_t bytes) -> void* {
    void* p = base + off;
    off += (bytes + 255) & ~(size_t)255;
    return p;
  };
  u16* qhh = (u16*)alloc(EL * 2);                      // q f16 (scaled)
  u16* khh = (u16*)alloc(ELP * 2);                     // k f16 (padded rows)
  u16* vbh = (u16*)alloc(EL * 2);                      // v f16 row-major
  u16* vth = (u16*)alloc((size_t)64 * 64 * NP * 2);    // v^T f16 padded cols
  u16* xh  = (u16*)alloc(EL * 2);                      // x / attn-out f16 hi
  u16* xl  = (u16*)alloc(EL * 2);                      // x / attn-out f16 lo
  u16* wq  = (u16*)alloc((size_t)3072 * 1024 * 2);     // w_qkv f16
  u16* wf  = (u16*)alloc((size_t)1024 * 1024 * 2);     // w_fc f16
  float2* cst = (float2*)alloc((size_t)B * 2048 * 32 * 8);

  // 1. split x to f16 hi/lo; cast weights to f16; build cos/sin table
  splitf16_kernel<<<2048, 256, 0, stream>>>(x, xh, xl, EL / 4);
  castf16_kernel<<<1024, 256, 0, stream>>>(w_qkv, wq, (long)3072 * 1024 / 4);
  castf16_kernel<<<256, 256, 0, stream>>>(w_fc, wf, (long)1024 * 1024 / 4);
  cs_table_kernel<<<(B * 2048 * 32) / 256, 256, 0, stream>>>(pos, cst);
  // 2. fused QKV projection (3-buffer counted-vmcnt f16x2) with fused RoPE + f16 epilogue
  //    grid = 33 M-tiles x 24 N-tiles = 792 (792 % 8 == 0)
  gemm_p3<0><<<dim3(792), 512, 0, stream>>>(xh, xl, wq, b_qkv, cst, nullptr,
                                            qhh, khh, vbh, 8196, 3072, 1024, N, NP);
  // 3. pad K rows [N,NP); transpose+pad V (f16 -> [bh][64][NP])
  kpad_kernel<<<(64 * (NP - N) * 32 + 255) / 256, 256, 0, stream>>>(khh, N, NP);
  vtransT_kernel<<<dim3(NP / 64, 64), 256, 0, stream>>>(vbh, vth, N, NP);
  // 4. flash attention (f16 core, 8-wave/256-row blocks) -> f16 hi/lo, reusing xh/xl
  attn_kernel<<<dim3(576), 512, 0, stream>>>(qhh, khh, vth, xh, xl, N, NP);
  // 5. output projection -> d_out  (33 x 8 = 264 blocks, 264 % 8 == 0)
  gemm_p3<1><<<dim3(264), 512, 0, stream>>>(xh, xl, wf, b_fc, nullptr,
                                            (float*)d_out, nullptr, nullptr, nullptr,
                                            8196, 1024, 1024, N, NP);
}

// Round 11
// 369.089 us; speedup vs baseline: 1.3406x; 1.3406x over previous
//
#include <hip/hip_runtime.h>

typedef unsigned short u16;
typedef __attribute__((ext_vector_type(8))) _Float16 f16x8;
typedef __attribute__((ext_vector_type(4))) float f32x4;

#define MFMAH(a, b, c) __builtin_amdgcn_mfma_f32_16x16x32_f16((a), (b), (c), 0, 0, 0)

__device__ __forceinline__ u16 f2h(float f) {
  _Float16 h = (_Float16)f;  // v_cvt_f16_f32, RNE
  return __builtin_bit_cast(u16, h);
}
__device__ __forceinline__ float h2f(u16 h) {
  return (float)__builtin_bit_cast(_Float16, h);
}
__device__ __forceinline__ unsigned pk_h(float a, float b) {
  return (unsigned)f2h(a) | ((unsigned)f2h(b) << 16);
}

// ---------------- fp32 -> f16 hi + f16 lo (exact to ~2^-23) ----------------
__global__ void splitf16_kernel(const float* __restrict__ in, u16* __restrict__ hi,
                                u16* __restrict__ lo, long n4) {
  long stride = (long)gridDim.x * blockDim.x;
  for (long i = (long)blockIdx.x * blockDim.x + threadIdx.x; i < n4; i += stride) {
    float4 v = ((const float4*)in)[i];
    ushort4 h, l;
    h.x = f2h(v.x); l.x = f2h(v.x - h2f(h.x));
    h.y = f2h(v.y); l.y = f2h(v.y - h2f(h.y));
    h.z = f2h(v.z); l.z = f2h(v.z - h2f(h.z));
    h.w = f2h(v.w); l.w = f2h(v.w - h2f(h.w));
    ((ushort4*)hi)[i] = h;
    ((ushort4*)lo)[i] = l;
  }
}

// ---------------- fp32 -> f16 single ----------------
__global__ void castf16_kernel(const float* __restrict__ in, u16* __restrict__ out, long n4) {
  long stride = (long)gridDim.x * blockDim.x;
  for (long i = (long)blockIdx.x * blockDim.x + threadIdx.x; i < n4; i += stride) {
    float4 v = ((const float4*)in)[i];
    ushort4 h;
    h.x = f2h(v.x); h.y = f2h(v.y); h.z = f2h(v.z); h.w = f2h(v.w);
    ((ushort4*)out)[i] = h;
  }
}

// ---------------- cos/sin table: (b, t-1, i) -> float2(c,s); 16 heads share positions ----------------
__global__ void cs_table_kernel(const int* __restrict__ pos, float2* __restrict__ cst) {
  int idx = blockIdx.x * 256 + threadIdx.x;  // exactly B*2048*32 threads
  int i = idx & 31;
  int r = idx >> 5;
  int ti = r & 2047;
  int b = r >> 11;
  int p = pos[b * 2048 + ti];
  // replicate reference fp32 rounding of freq and angle, then exact trig
  float fr = (float)pow(10000.0, -(double)i / 32.0);
  float angf = (float)p * fr;
  double sd, cd;
  sincos((double)angf, &sd, &cd);
  cst[idx] = make_float2((float)cd, (float)sd);
}

// ---------------- K pad rows [N, NP): zero (f16 single) ----------------
__global__ void kpad_kernel(u16* __restrict__ kh, int N, int NP) {
  const int per_bh = (NP - N) * 32;  // u32 words per bh
  int idx = blockIdx.x * 256 + threadIdx.x;
  if (idx >= 64 * per_bh) return;
  int bh = idx / per_bh, r = idx - bh * per_bh;
  size_t u = (((size_t)bh * NP + N) * 64 >> 1) + r;
  ((unsigned*)kh)[u] = 0;
}

// ---------------- V transpose: f16 [bh][N][64] -> [bh][64][NP], zero-padded ----------------
__global__ __launch_bounds__(256) void vtransT_kernel(const u16* __restrict__ vb_,
                                                      u16* __restrict__ ot, int N, int NP) {
  __shared__ u16 tile[64][72];
  const int bh = blockIdx.y;
  const int t0 = blockIdx.x * 64;
  const u16* ih = vb_ + (size_t)bh * N * 64;
#pragma unroll
  for (int p = 0; p < 4; ++p) {
    int idx = p * 256 + threadIdx.x;  // 1024 chunks of 4 u16
    int tloc = idx >> 4, c = (idx & 15) * 4;
    int t = t0 + tloc;
    ushort4 a = make_ushort4(0, 0, 0, 0);
    if (t < N) a = *(const ushort4*)(ih + (size_t)t * 64 + c);
    *(ushort4*)&tile[tloc][c] = a;
  }
  __syncthreads();
  u16* oh = ot + (size_t)bh * 64 * NP;
#pragma unroll
  for (int p = 0; p < 4; ++p) {
    int idx = p * 256 + threadIdx.x;  // d (64) x tquad (16)
    int d = idx >> 4, tq = (idx & 15) * 4;
    int t = t0 + tq;
    if (t < NP) {
      ushort4 a;
      a.x = tile[tq + 0][d]; a.y = tile[tq + 1][d];
      a.z = tile[tq + 2][d]; a.w = tile[tq + 3][d];
      *(ushort4*)(oh + (size_t)d * NP + t) = a;
    }
  }
}

// ================= GEMM common (R8 structure: 2-phase, 256 thr, BM=128, LDS-occupancy-first) =====
// R9/R10 lesson: 3 blocks/CU simple 2-phase beats 8-phase / counted-vmcnt at 1 block/CU —
// occupancy dominates schedule sophistication.  R8 accounting: wall = LDS throughput, so
// gemm_a1 cuts LDS bytes (A single f16) instead of re-scheduling.  T2 source-swizzle kept.
__device__ __forceinline__ int swz_off(int R, int lg) {
  return R * 32 + ((lg ^ ((R >> 1) & 3)) << 3);
}
__device__ __forceinline__ void stage_tile(const u16* __restrict__ g, u16* l,
                                           int row0, int rmax, int K, int k0, int tid) {
#pragma unroll
  for (int t = 0; t < 2; ++t) {
    int c = t * 256 + tid;
    int row = c >> 2;
    int kc = (((c & 3) ^ ((c >> 3) & 3)) << 3);  // pre-swizzled source granule
    int gr = row0 + row;
    if (gr > rmax) gr = rmax;
    const u16* gp = g + (size_t)gr * K + (k0 + kc);
    __builtin_amdgcn_global_load_lds((const __attribute__((address_space(1))) void*)gp,
                                     (__attribute__((address_space(3))) void*)(l + c * 8),
                                     16, 0, 0);
  }
}

// ---- gemm_a1: A single f16 (QKV; x-rounding within error budget).  LDS 32KB -> 5 blocks/CU ----
__global__ __launch_bounds__(256) void gemm_a1(
    const u16* __restrict__ Aw, const u16* __restrict__ Bw,
    const float* __restrict__ bias, const float2* __restrict__ cst,
    u16* __restrict__ oq, u16* __restrict__ ok, u16* __restrict__ ov,
    int M, int Nn, int K, int Ntok, int NP) {
  __shared__ u16 A0[4096], B0[4096], A1[4096], B1[4096];
  const int tid = threadIdx.x;
  const int wid = tid >> 6, lane = tid & 63;
  const int wm = wid >> 1, wn = wid & 1;
  const int lg = lane >> 4, lm = lane & 15;
  const int id = blockIdx.x;
  const int chunk = (int)gridDim.x >> 3, nx = Nn >> 7;
  const int swz = (id & 7) * chunk + (id >> 3);  // XCD-bijective
  const int mbase = (swz / nx) * 128, nbase = (swz % nx) * 128;

  f32x4 acc[4][4];
  const f32x4 zero = {0.f, 0.f, 0.f, 0.f};
#pragma unroll
  for (int a = 0; a < 4; ++a)
#pragma unroll
    for (int b = 0; b < 4; ++b) acc[a][b] = zero;

  stage_tile(Aw, A0, mbase, M - 1, K, 0, tid);
  stage_tile(Bw, B0, nbase, Nn - 1, K, 0, tid);
  __syncthreads();

  for (int k0 = 0; k0 < K; k0 += 64) {
    if (k0 + 32 < K) {
      stage_tile(Aw, A1, mbase, M - 1, K, k0 + 32, tid);
      stage_tile(Bw, B1, nbase, Nn - 1, K, k0 + 32, tid);
    }
    {
      f16x8 a[4], w[4];
#pragma unroll
      for (int f = 0; f < 4; ++f) {
        a[f] = *(const f16x8*)&A0[swz_off(wm * 64 + f * 16 + lm, lg)];
        w[f] = *(const f16x8*)&B0[swz_off(wn * 64 + f * 16 + lm, lg)];
      }
#pragma unroll
      for (int fm = 0; fm < 4; ++fm)
#pragma unroll
        for (int fn = 0; fn < 4; ++fn) acc[fm][fn] = MFMAH(a[fm], w[fn], acc[fm][fn]);
    }
    __syncthreads();
    if (k0 + 64 < K) {
      stage_tile(Aw, A0, mbase, M - 1, K, k0 + 64, tid);
      stage_tile(Bw, B0, nbase, Nn - 1, K, k0 + 64, tid);
    }
    {
      f16x8 a[4], w[4];
#pragma unroll
      for (int f = 0; f < 4; ++f) {
        a[f] = *(const f16x8*)&A1[swz_off(wm * 64 + f * 16 + lm, lg)];
        w[f] = *(const f16x8*)&B1[swz_off(wn * 64 + f * 16 + lm, lg)];
      }
#pragma unroll
      for (int fm = 0; fm < 4; ++fm)
#pragma unroll
        for (int fn = 0; fn < 4; ++fn) acc[fm][fn] = MFMAH(a[fm], w[fn], acc[fm][fn]);
    }
    __syncthreads();
  }

  const int which = nbase >> 10;  // block-uniform q/k/v select
  const bool odd = (lm & 1);
#pragma unroll
  for (int fm = 0; fm < 4; ++fm)
#pragma unroll
    for (int fn = 0; fn < 4; ++fn) {
      int col = nbase + wn * 64 + fn * 16 + lm;
      float bv = bias[col];
      int h2 = (col >> 6) & 15, d2 = col & 63;
#pragma unroll
      for (int i = 0; i < 4; ++i) {
        int row = mbase + wm * 64 + fm * 16 + lg * 4 + i;
        float v = acc[fm][fn][i] + bv;
        float partner = __shfl_xor(v, 1);  // neighbor column (re<->im), uniform exec
        if (row < M) {
          int b2 = row / Ntok, t2 = row - b2 * Ntok;
          int bh2 = b2 * 16 + h2;
          if (which == 2) {  // v: f16 row-major
            ov[((size_t)bh2 * Ntok + t2) * 64 + d2] = f2h(v);
          } else {
            float out = v;
            if (t2 > 0) {
              float2 cs = cst[((size_t)(b2 << 11) + (t2 - 1)) * 32 + (d2 >> 1)];
              out = v * cs.x + (odd ? partner * cs.y : -partner * cs.y);
            }
            if (which == 0) {  // q: fold softmax scale & exp2 conversion
              out *= 0.18033688011112042f;  // 0.125 * log2(e)
              oq[((size_t)bh2 * Ntok + t2) * 64 + d2] = f2h(out);
            } else {  // k: padded row allocation [bh][NP][64]
              ok[((size_t)bh2 * NP + t2) * 64 + d2] = f2h(out);
            }
          }
        }
      }
    }
}

// ---- gemm_a2: A = f16 hi/lo (FC; exact attn-out), fp32 row-major out.  LDS 48KB -> 3 blocks/CU ----
__global__ __launch_bounds__(256) void gemm_a2(
    const u16* __restrict__ Ah, const u16* __restrict__ Al, const u16* __restrict__ Bw,
    const float* __restrict__ bias, float* __restrict__ outf, int M, int Nn, int K) {
  __shared__ u16 A0h[4096], A0l[4096], B0w[4096];
  __shared__ u16 A1h[4096], A1l[4096], B1w[4096];
  const int tid = threadIdx.x;
  const int wid = tid >> 6, lane = tid & 63;
  const int wm = wid >> 1, wn = wid & 1;
  const int lg = lane >> 4, lm = lane & 15;
  const int id = blockIdx.x;
  const int chunk = (int)gridDim.x >> 3, nx = Nn >> 7;
  const int swz = (id & 7) * chunk + (id >> 3);
  const int mbase = (swz / nx) * 128, nbase = (swz % nx) * 128;

  f32x4 acc[4][4];
  const f32x4 zero = {0.f, 0.f, 0.f, 0.f};
#pragma unroll
  for (int a = 0; a < 4; ++a)
#pragma unroll
    for (int b = 0; b < 4; ++b) acc[a][b] = zero;

  stage_tile(Ah, A0h, mbase, M - 1, K, 0, tid);
  stage_tile(Al, A0l, mbase, M - 1, K, 0, tid);
  stage_tile(Bw, B0w, nbase, Nn - 1, K, 0, tid);
  __syncthreads();

  for (int k0 = 0; k0 < K; k0 += 64) {
    if (k0 + 32 < K) {
      stage_tile(Ah, A1h, mbase, M - 1, K, k0 + 32, tid);
      stage_tile(Al, A1l, mbase, M - 1, K, k0 + 32, tid);
      stage_tile(Bw, B1w, nbase, Nn - 1, K, k0 + 32, tid);
    }
    {
      f16x8 ah[4], al[4], w[4];
#pragma unroll
      for (int f = 0; f < 4; ++f) {
        ah[f] = *(const f16x8*)&A0h[swz_off(wm * 64 + f * 16 + lm, lg)];
        al[f] = *(const f16x8*)&A0l[swz_off(wm * 64 + f * 16 + lm, lg)];
        w[f] = *(const f16x8*)&B0w[swz_off(wn * 64 + f * 16 + lm, lg)];
      }
#pragma unroll
      for (int fm = 0; fm < 4; ++fm)
#pragma unroll
        for (int fn = 0; fn < 4; ++fn) {
          acc[fm][fn] = MFMAH(ah[fm], w[fn], acc[fm][fn]);
          acc[fm][fn] = MFMAH(al[fm], w[fn], acc[fm][fn]);
        }
    }
    __syncthreads();
    if (k0 + 64 < K) {
      stage_tile(Ah, A0h, mbase, M - 1, K, k0 + 64, tid);
      stage_tile(Al, A0l, mbase, M - 1, K, k0 + 64, tid);
      stage_tile(Bw, B0w, nbase, Nn - 1, K, k0 + 64, tid);
    }
    {
      f16x8 ah[4], al[4], w[4];
#pragma unroll
      for (int f = 0; f < 4; ++f) {
        ah[f] = *(const f16x8*)&A1h[swz_off(wm * 64 + f * 16 + lm, lg)];
        al[f] = *(const f16x8*)&A1l[swz_off(wm * 64 + f * 16 + lm, lg)];
        w[f] = *(const f16x8*)&B1w[swz_off(wn * 64 + f * 16 + lm, lg)];
      }
#pragma unroll
      for (int fm = 0; fm < 4; ++fm)
#pragma unroll
        for (int fn = 0; fn < 4; ++fn) {
          acc[fm][fn] = MFMAH(ah[fm], w[fn], acc[fm][fn]);
          acc[fm][fn] = MFMAH(al[fm], w[fn], acc[fm][fn]);
        }
    }
    __syncthreads();
  }

#pragma unroll
  for (int fm = 0; fm < 4; ++fm)
#pragma unroll
    for (int fn = 0; fn < 4; ++fn) {
      int col = nbase + wn * 64 + fn * 16 + lm;
      float bv = bias[col];
#pragma unroll
      for (int i = 0; i < 4; ++i) {
        int row = mbase + wm * 64 + fm * 16 + lg * 4 + i;
        if (row < M) outf[(size_t)row * Nn + col] = acc[fm][fn][i] + bv;
      }
    }
}

// ---------------- flash attention v5: 8-wave blocks, 256 q-rows, KVBLK=64, 2-phase ----------------
// K tile LDS (8KB): chunk rK*64+key -> K[key][rK*8..+8]  (rK = d-octet 0..7)
// V tile LDS (8KB): chunk kr*64+d   -> V^T[d][kv+kr*8..+8] (kr = key-octet 0..7)
template <bool DO_STAGE, bool TAIL>
__device__ __forceinline__ void attn_tile(
    int kv0, int kvn,
    const u16* Kc, const u16* Vc, u16* Kn, u16* Vn,
    const u16* kgb, const u16* vgb,
    int tid, int lg, int lm, int kvbase,
    const f16x8 (&qf16)[2][2],
    float (&m_)[2], float (&l_)[2], f32x4 (&oacc)[2][4],
    unsigned (*pexw)[4], int N) {
  if (DO_STAGE) {  // stage NEXT tile (other buffer); latency hides under this tile's compute
    __builtin_amdgcn_global_load_lds(
        (const __attribute__((address_space(1))) void*)(kgb + (size_t)kvn * 64),
        (__attribute__((address_space(3))) void*)(Kn + tid * 8), 16, 0, 0);
    __builtin_amdgcn_global_load_lds(
        (const __attribute__((address_space(1))) void*)(vgb + kvn),
        (__attribute__((address_space(3))) void*)(Vn + tid * 8), 16, 0, 0);
  }

  const f32x4 zero = {0.f, 0.f, 0.f, 0.f};
  f32x4 s[2][4];
#pragma unroll
  for (int qf = 0; qf < 2; ++qf)
#pragma unroll
    for (int cf = 0; cf < 4; ++cf) s[qf][cf] = zero;
#pragma unroll
  for (int cf = 0; cf < 4; ++cf)
#pragma unroll
    for (int dk = 0; dk < 2; ++dk) {
      f16x8 kf = *(const f16x8*)&Kc[kvbase + dk * 2048 + cf * 128];
      s[0][cf] = MFMAH(kf, qf16[0][dk], s[0][cf]);
      s[1][cf] = MFMAH(kf, qf16[1][dk], s[1][cf]);
    }
  if (TAIL) {
#pragma unroll
    for (int qf = 0; qf < 2; ++qf)
#pragma unroll
      for (int cf = 0; cf < 4; ++cf)
#pragma unroll
        for (int i = 0; i < 4; ++i)
          if (kv0 + cf * 16 + lg * 4 + i >= N) s[qf][cf][i] = -1e30f;
  }

  f16x8 pb[2][2];  // [qf][ks]
  const int ga = (lg & 1) * 2, gb = ga + 1;
  const int cfs2 = (lg >> 1) * 2;
#pragma unroll
  for (int qf = 0; qf < 2; ++qf) {
    float mx = s[qf][0][0];
#pragma unroll
    for (int cf = 0; cf < 4; ++cf)
#pragma unroll
      for (int i = 0; i < 4; ++i) mx = fmaxf(mx, s[qf][cf][i]);
    mx = fmaxf(mx, __shfl_xor(mx, 16));
    mx = fmaxf(mx, __shfl_xor(mx, 32));
    float mr = m_[qf];
    bool nore = __all(mx - mr <= 8.f) != 0;  // defer-max, THR=8 in log2 domain
    float mnew = nore ? mr : fmaxf(mr, mx);
    float p[16];
#pragma unroll
    for (int cf = 0; cf < 4; ++cf)
#pragma unroll
      for (int i = 0; i < 4; ++i)
        p[cf * 4 + i] = __builtin_amdgcn_exp2f(s[qf][cf][i] - mnew);
    float ps = 0.f;
#pragma unroll
    for (int j = 0; j < 16; ++j) ps += p[j];
    ps += __shfl_xor(ps, 16);
    ps += __shfl_xor(ps, 32);
    if (nore) {
      l_[qf] += ps;
    } else {
      float sc = __builtin_amdgcn_exp2f(mr - mnew);
      l_[qf] = l_[qf] * sc + ps;
      m_[qf] = mnew;
#pragma unroll
      for (int c = 0; c < 4; ++c)
#pragma unroll
        for (int i = 0; i < 4; ++i) oacc[qf][c][i] *= sc;
    }
    // pack P -> f16, redistribute to B-frag via wave-private LDS (DS in-order per wave)
#pragma unroll
    for (int ks = 0; ks < 2; ++ks) {
      uint4 uw;
      uw.x = pk_h(p[ks * 8 + 0], p[ks * 8 + 1]);
      uw.y = pk_h(p[ks * 8 + 2], p[ks * 8 + 3]);
      uw.z = pk_h(p[ks * 8 + 4], p[ks * 8 + 5]);
      uw.w = pk_h(p[ks * 8 + 6], p[ks * 8 + 7]);
      *(uint4*)&pexw[lg * 16 + lm][0] = uw;
      uint2 r0 = *(const uint2*)&pexw[ga * 16 + lm][cfs2];
      uint2 r1 = *(const uint2*)&pexw[gb * 16 + lm][cfs2];
      uint4 pu = make_uint4(r0.x, r0.y, r1.x, r1.y);
      pb[qf][ks] = __builtin_bit_cast(f16x8, pu);
    }
  }

#pragma unroll
  for (int c = 0; c < 4; ++c)
#pragma unroll
    for (int ks = 0; ks < 2; ++ks) {
      f16x8 vh = *(const f16x8*)&Vc[kvbase + ks * 2048 + c * 128];
      oacc[0][c] = MFMAH(vh, pb[0][ks], oacc[0][c]);
      oacc[1][c] = MFMAH(vh, pb[1][ks], oacc[1][c]);
    }
}

__global__ __launch_bounds__(512, 4) void attn_kernel(
    const u16* __restrict__ qh, const u16* __restrict__ kh, const u16* __restrict__ vth,
    u16* __restrict__ outh, u16* __restrict__ outl, int N, int NP) {
  __shared__ u16 K0[4096], V0[4096], K1[4096], V1[4096];
  __shared__ unsigned pexm[8][64][4];

  const int id = blockIdx.x;
  const int swz = (id & 7) * 72 + (id >> 3);  // XCD-bijective (576 = 8*72)
  const int qblk = swz % 9;
  const int bh = swz / 9;
  const int b = bh >> 4, h = bh & 15;
  const int tid = threadIdx.x;
  const int wid = tid >> 6, lane = tid & 63;
  const int lg = lane >> 4, lm = lane & 15;
  const int qbase = qblk * 256 + wid * 32;
  const size_t qoff = (size_t)bh * N * 64;
  const size_t koff = (size_t)bh * NP * 64;
  const size_t voff = (size_t)bh * 64 * NP;

  const int jK = tid & 63, rK = tid >> 6;
  const u16* kgb = kh + koff + (size_t)jK * 64 + rK * 8;
  const u16* vgb = vth + voff + (size_t)jK * NP + rK * 8;
  const int kvbase = lg * 512 + lm * 8;  // + dk|ks*2048 + cf|c*128

  f16x8 qf16[2][2];
#pragma unroll
  for (int qf = 0; qf < 2; ++qf) {
    int qr = qbase + qf * 16 + lm;
    if (qr > N - 1) qr = N - 1;
    const u16* qp = qh + qoff + (size_t)qr * 64 + lg * 8;
    qf16[qf][0] = *(const f16x8*)(qp);
    qf16[qf][1] = *(const f16x8*)(qp + 32);
  }

  const f32x4 zero = {0.f, 0.f, 0.f, 0.f};
  f32x4 oacc[2][4];
#pragma unroll
  for (int qf = 0; qf < 2; ++qf)
#pragma unroll
    for (int c = 0; c < 4; ++c) oacc[qf][c] = zero;
  float m_[2] = {-1e30f, -1e30f}, l_[2] = {0.f, 0.f};
  unsigned(*pexw)[4] = &pexm[wid][0];

  __builtin_amdgcn_global_load_lds(
      (const __attribute__((address_space(1))) void*)kgb,
      (__attribute__((address_space(3))) void*)(K0 + tid * 8), 16, 0, 0);
  __builtin_amdgcn_global_load_lds(
      (const __attribute__((address_space(1))) void*)vgb,
      (__attribute__((address_space(3))) void*)(V0 + tid * 8), 16, 0, 0);
  asm volatile("s_waitcnt vmcnt(0)" ::: "memory");
  __builtin_amdgcn_s_barrier();

  for (int t = 0; t < 32; t += 2) {
    attn_tile<true, false>(t * 64, (t + 1) * 64, K0, V0, K1, V1, kgb, vgb,
                           tid, lg, lm, kvbase, qf16, m_, l_, oacc, pexw, N);
    asm volatile("s_waitcnt vmcnt(0)" ::: "memory");
    __builtin_amdgcn_s_barrier();
    attn_tile<true, false>((t + 1) * 64, (t + 2) * 64, K1, V1, K0, V0, kgb, vgb,
                           tid, lg, lm, kvbase, qf16, m_, l_, oacc, pexw, N);
    asm volatile("s_waitcnt vmcnt(0)" ::: "memory");
    __builtin_amdgcn_s_barrier();
  }
  attn_tile<false, true>(32 * 64, 0, K0, V0, K1, V1, kgb, vgb,
                         tid, lg, lm, kvbase, qf16, m_, l_, oacc, pexw, N);

  // epilogue: O/l -> f16 hi/lo (feeds FC's exact hi/lo A)
#pragma unroll
  for (int qf = 0; qf < 2; ++qf) {
    int t = qbase + qf * 16 + lm;
    if (t < N) {
      float rl = 1.f / l_[qf];
      size_t rowoff = ((size_t)(b * N + t)) * 1024 + h * 64 + lg * 4;
#pragma unroll
      for (int c = 0; c < 4; ++c) {
        float v0 = oacc[qf][c][0] * rl, v1 = oacc[qf][c][1] * rl;
        float v2 = oacc[qf][c][2] * rl, v3 = oacc[qf][c][3] * rl;
        u16 h0 = f2h(v0), h1 = f2h(v1), h2 = f2h(v2), h3 = f2h(v3);
        unsigned hh01 = (unsigned)h0 | ((unsigned)h1 << 16);
        unsigned hh23 = (unsigned)h2 | ((unsigned)h3 << 16);
        unsigned ll01 = pk_h(v0 - h2f(h0), v1 - h2f(h1));
        unsigned ll23 = pk_h(v2 - h2f(h2), v3 - h2f(h3));
        *(uint2*)(outh + rowoff + c * 16) = make_uint2(hh01, hh23);
        *(uint2*)(outl + rowoff + c * 16) = make_uint2(ll01, ll23);
      }
    }
  }
}

// ---------------- orchestration ----------------
extern "C" void kernel_launch(void* const* d_in, const int* in_sizes, int n_in,
                              void* d_out, int out_size, void* d_ws, size_t ws_size,
                              hipStream_t stream) {
  const float* x     = (const float*)d_in[0];
  const int*   pos   = (const int*)  d_in[1];
  const float* w_qkv = (const float*)d_in[2];
  const float* b_qkv = (const float*)d_in[3];
  const float* w_fc  = (const float*)d_in[4];
  const float* b_fc  = (const float*)d_in[5];
  (void)in_sizes; (void)n_in; (void)out_size; (void)ws_size;

  const int B = 4, N = 2049, NP = 2112;  // NP = 33*64 (KVBLK=64 tiles)
  const long EL = (long)B * N * 1024;       // 8,392,704
  const long ELP = (long)B * 16 * NP * 64;  // padded K elems

  char* base = (char*)d_ws;
  size_t off = 0;
  auto alloc = [&](size_t bytes) -> void* {
    void* p = base + off;
    off += (bytes + 255) & ~(size_t)255;
    return p;
  };
  u16* qhh = (u16*)alloc(EL * 2);                      // q f16 (scaled)
  u16* khh = (u16*)alloc(ELP * 2);                     // k f16 (padded rows)
  u16* vbh = (u16*)alloc(EL * 2);                      // v f16 row-major
  u16* vth = (u16*)alloc((size_t)64 * 64 * NP * 2);    // v^T f16 padded cols
  u16* xh  = (u16*)alloc(EL * 2);                      // x f16 / attn-out f16 hi
  u16* xl  = (u16*)alloc(EL * 2);                      // attn-out f16 lo
  u16* wq  = (u16*)alloc((size_t)3072 * 1024 * 2);     // w_qkv f16
  u16* wf  = (u16*)alloc((size_t)1024 * 1024 * 2);     // w_fc f16
  float2* cst = (float2*)alloc((size_t)B * 2048 * 32 * 8);

  // 1. cast x + weights to f16; build cos/sin table
  castf16_kernel<<<2048, 256, 0, stream>>>(x, xh, EL / 4);
  castf16_kernel<<<1024, 256, 0, stream>>>(w_qkv, wq, (long)3072 * 1024 / 4);
  castf16_kernel<<<256, 256, 0, stream>>>(w_fc, wf, (long)1024 * 1024 / 4);
  cs_table_kernel<<<(B * 2048 * 32) / 256, 256, 0, stream>>>(pos, cst);
  // 2. fused QKV projection (A single f16) with fused RoPE + f16 q/k/v epilogue
  //    grid = 65 M-tiles x 24 N-tiles = 1560 (1560 % 8 == 0)
  gemm_a1<<<dim3(1560), 256, 0, stream>>>(xh, wq, b_qkv, cst,
                                          qhh, khh, vbh, 8196, 3072, 1024, N, NP);
  // 3. pad K rows [N,NP); transpose+pad V (f16 -> [bh][64][NP])
  kpad_kernel<<<(64 * (NP - N) * 32 + 255) / 256, 256, 0, stream>>>(khh, N, NP);
  vtransT_kernel<<<dim3(NP / 64, 64), 256, 0, stream>>>(vbh, vth, N, NP);
  // 4. flash attention (f16 core, 8-wave/256-row blocks) -> f16 hi/lo into xh/xl
  attn_kernel<<<dim3(576), 512, 0, stream>>>(qhh, khh, vth, xh, xl, N, NP);
  // 5. output projection (A = attn-out hi/lo, exact) -> d_out; grid = 65 x 8 = 520
  gemm_a2<<<dim3(520), 256, 0, stream>>>(xh, xl, wf, b_fc,
                                         (float*)d_out, 8196, 1024, 1024);
}